// Round 4
// baseline (150.529 us; speedup 1.0000x reference)
//
#include <hip/hip_runtime.h>

// Hierarchical softmax: B=4096, NHID=512, BR=32, DEPTH=3, V=32768.
// bucket g = lab>>5 (1024 buckets). For bucket g:
//   node0=0 (step g>>5), node1=1+(g>>5) (step g&31), node2=33+g (step lab&31)
// out[b] = prod_k softmax(x_b @ W[node_k])[step_k]
//
// R4: one block per bucket (self-compacting). All THREE node W-streams are
// fused into a single 16-iteration inner loop (one barrier per chunk instead
// of 8) so global loads from the 3 streams pipeline together -> ~3x fewer
// latency stall rounds. SMAX=4 keeps acc pressure at 48 VGPRs (<=128 total,
// 16 waves/CU) and reduces padded work vs SMAX=8.

#define NHID  512
#define BR    32
#define BATCH 4096
#define NBUCK 1024
#define SMAX  4     // samples per pass
#define SCAP  64    // bucket capacity; P(n>64) ~ 0 for uniform 4096->1024

// DPP butterfly add over lane xor 1 / xor 2 (quad_perm, pure VALU)
__device__ __forceinline__ float dpp_xadd1(float v) {
    int m = __builtin_amdgcn_update_dpp(0, __float_as_int(v), 0xB1, 0xF, 0xF, true);
    return v + __int_as_float(m);
}
__device__ __forceinline__ float dpp_xadd2(float v) {
    int m = __builtin_amdgcn_update_dpp(0, __float_as_int(v), 0x4E, 0xF, 0xF, true);
    return v + __int_as_float(m);
}

#define FMA4(A, xv, wv_) do { \
    (A).x = fmaf((xv), (wv_).x, (A).x); \
    (A).y = fmaf((xv), (wv_).y, (A).y); \
    (A).z = fmaf((xv), (wv_).z, (A).z); \
    (A).w = fmaf((xv), (wv_).w, (A).w); } while (0)

__global__ __launch_bounds__(256, 4) void hsm_fused(
    const float* __restrict__ inputs,
    const int* __restrict__ labels,
    const float* __restrict__ W,
    float* __restrict__ out)
{
    __shared__ float xsT[NHID * SMAX];             // 8 KB   xsT[h][s]
    __shared__ float partial[8 * 3 * SMAX * BR];   // 12 KB  partial[wq][k][s][col]
    __shared__ float pk[3][SMAX];
    __shared__ int   slist[SCAP];                  // (sample_idx<<5) | (lab&31)
    __shared__ int   scount;

    const int g   = blockIdx.x;
    const int tid = threadIdx.x;

    if (tid == 0) scount = 0;
    __syncthreads();

    // ---- self-compaction: find this bucket's samples ----
    #pragma unroll
    for (int r = 0; r < BATCH / 256; ++r) {
        int j = tid + 256 * r;
        int lab = labels[j];
        if ((lab >> 5) == g) {
            int p = atomicAdd(&scount, 1);
            if (p < SCAP) slist[p] = (j << 5) | (lab & 31);
        }
    }
    __syncthreads();
    const int n = min(scount, SCAP);
    if (n == 0) return;

    const int wv   = tid >> 6;     // wave = h-quarter (0..3)
    const int lane = tid & 63;
    const int hsel = lane & 7;     // h strip within 8 consecutive rows
    const int colg = lane >> 3;    // float4 column group (0..7)

    const int node1 = 1 + (g >> 5);
    const int node2 = 33 + g;

    // lane covers h = 128*wv + 8*i + hsel, cols [4*colg, 4*colg+4)
    const size_t laneoff = (size_t)wv * 1024 + hsel * 8 + colg;
    const float4* wp0 = (const float4*)W + laneoff;
    const float4* wp1 = (const float4*)(W + (size_t)node1 * (NHID * BR)) + laneoff;
    const float4* wp2 = (const float4*)(W + (size_t)node2 * (NHID * BR)) + laneoff;
    const float4* xs4 = (const float4*)xsT;

    for (int c0 = 0; c0 < n; c0 += SMAX) {
        const int m = min(SMAX, n - c0);

        __syncthreads();   // xsT reuse guard
        // ---- stage x transposed: xsT[h][s] (zero-pad unused slots) ----
        #pragma unroll
        for (int r = 0; r < 2; ++r) {
            int h = tid + 256 * r;
            float v[SMAX];
            #pragma unroll
            for (int s = 0; s < SMAX; ++s) {
                float x = 0.0f;
                if (s < m) {
                    int sid = slist[c0 + s] >> 5;
                    x = inputs[(size_t)sid * NHID + h];
                }
                v[s] = x;
            }
            ((float4*)xsT)[h] = make_float4(v[0], v[1], v[2], v[3]);
        }
        __syncthreads();

        // ---- fused 3-node W stream ----
        float4 acc[3][SMAX];
        #pragma unroll
        for (int k = 0; k < 3; ++k)
            #pragma unroll
            for (int s = 0; s < SMAX; ++s) acc[k][s] = make_float4(0, 0, 0, 0);

        #pragma unroll 4
        for (int i = 0; i < 16; ++i) {
            float4 w0 = wp0[i * 64];
            float4 w1 = wp1[i * 64];
            float4 w2 = wp2[i * 64];
            float4 x4 = xs4[wv * 128 + i * 8 + hsel];
            FMA4(acc[0][0], x4.x, w0); FMA4(acc[0][1], x4.y, w0);
            FMA4(acc[0][2], x4.z, w0); FMA4(acc[0][3], x4.w, w0);
            FMA4(acc[1][0], x4.x, w1); FMA4(acc[1][1], x4.y, w1);
            FMA4(acc[1][2], x4.z, w1); FMA4(acc[1][3], x4.w, w1);
            FMA4(acc[2][0], x4.x, w2); FMA4(acc[2][1], x4.y, w2);
            FMA4(acc[2][2], x4.z, w2); FMA4(acc[2][3], x4.w, w2);
        }

        // reduce over hsel bits 0,1 via DPP (VALU only)
        #pragma unroll
        for (int k = 0; k < 3; ++k) {
            #pragma unroll
            for (int s = 0; s < SMAX; ++s) {
                acc[k][s].x = dpp_xadd2(dpp_xadd1(acc[k][s].x));
                acc[k][s].y = dpp_xadd2(dpp_xadd1(acc[k][s].y));
                acc[k][s].z = dpp_xadd2(dpp_xadd1(acc[k][s].z));
                acc[k][s].w = dpp_xadd2(dpp_xadd1(acc[k][s].w));
            }
        }
        // 2 remaining partials per wave (hsel bit 2) -> LDS
        if ((lane & 3) == 0) {
            int wq = wv * 2 + ((lane >> 2) & 1);
            #pragma unroll
            for (int k = 0; k < 3; ++k)
                #pragma unroll
                for (int s = 0; s < SMAX; ++s)
                    *(float4*)&partial[((wq * 3 + k) * SMAX + s) * BR + colg * 4]
                        = acc[k][s];
        }
        __syncthreads();

        // ---- reducer + softmax: 128 threads = (s, col), loop k ----
        if (tid < 32 * SMAX) {
            int s   = tid >> 5;
            int col = tid & 31;
            #pragma unroll
            for (int k = 0; k < 3; ++k) {
                float l = 0.0f;
                #pragma unroll
                for (int wq = 0; wq < 8; ++wq)
                    l += partial[((wq * 3 + k) * SMAX + s) * BR + col];
                float mx = l;
                #pragma unroll
                for (int mm = 1; mm <= 16; mm <<= 1)
                    mx = fmaxf(mx, __shfl_xor(mx, mm));
                float e = expf(l - mx);
                float es = e;
                #pragma unroll
                for (int mm = 1; mm <= 16; mm <<= 1)
                    es += __shfl_xor(es, mm);
                int step = (k == 0) ? (g >> 5)
                         : (k == 1) ? (g & 31)
                                    : (slist[c0 + s] & 31);
                if (col == step) pk[k][s] = e / es;
            }
        }
        __syncthreads();

        // ---- combine levels, write out ----
        if (tid < m) {
            int sid = slist[c0 + tid] >> 5;
            out[sid] = pk[0][tid] * pk[1][tid] * pk[2][tid];
        }
    }
}

extern "C" void kernel_launch(void* const* d_in, const int* in_sizes, int n_in,
                              void* d_out, int out_size, void* d_ws, size_t ws_size,
                              hipStream_t stream)
{
    const float* inputs = (const float*)d_in[0];
    const int*   labels = (const int*)d_in[1];
    const float* W      = (const float*)d_in[2];
    float* out = (float*)d_out;

    hsm_fused<<<dim3(NBUCK), dim3(256), 0, stream>>>(inputs, labels, W, out);
}

// Round 5
// 132.404 us; speedup vs baseline: 1.1369x; 1.1369x over previous
//
#include <hip/hip_runtime.h>

// Hierarchical softmax: B=4096, NHID=512, BR=32, DEPTH=3, V=32768.
// node0=0, node1=1+(lab>>10), node2=33+(lab>>5)
// step0=(lab>>10)&31, step1=(lab>>5)&31, step2=lab&31
// out[b] = prod_k softmax(x_b @ W[node_k])[step_k]
//
// R5: R1's high-MLP sample-per-block kernel (proven 3.2 TB/s) + counting
// sort by level-2 node (single-block LDS sort) + XCD-aware rank swizzle:
// block b handles sorted rank (b&7)*512 + (b>>3), so contiguous sorted
// ranks (same bucket) land on one XCD -> node2's 64 KB is L2-resident for
// all its samples. HBM gather 171 MB -> ~70 MB; logical 768 MB served by L2.

#define NHID  512
#define BR    32
#define BATCH 4096
#define NBUCK 1024

// ---------- single-block counting sort by bucket = lab>>5 ----------
__global__ __launch_bounds__(1024) void k_sort(const int* __restrict__ labels,
                                               int* __restrict__ order) {
    __shared__ int labs[BATCH];   // 16 KB
    __shared__ int hist[NBUCK];   // 4 KB (reused as cursor)
    __shared__ int scn[NBUCK];    // 4 KB
    const int t = threadIdx.x;

    hist[t] = 0;
    #pragma unroll
    for (int r = 0; r < BATCH / 1024; ++r)
        labs[t + 1024 * r] = labels[t + 1024 * r];
    __syncthreads();
    #pragma unroll
    for (int r = 0; r < BATCH / 1024; ++r)
        atomicAdd(&hist[labs[t + 1024 * r] >> 5], 1);
    __syncthreads();

    const int cnt = hist[t];
    scn[t] = cnt;
    __syncthreads();
    for (int d = 1; d < NBUCK; d <<= 1) {
        int u = (t >= d) ? scn[t - d] : 0;
        __syncthreads();
        scn[t] += u;
        __syncthreads();
    }
    hist[t] = scn[t] - cnt;   // exclusive offset -> cursor
    __syncthreads();

    #pragma unroll
    for (int r = 0; r < BATCH / 1024; ++r) {
        int j = t + 1024 * r;
        int pos = atomicAdd(&hist[labs[j] >> 5], 1);
        order[pos] = j;
    }
}

// ---------- compute: one block per sample (sorted order) ----------
__global__ __launch_bounds__(192) void hsm_kernel(
    const float* __restrict__ inputs,
    const int* __restrict__ labels,
    const float* __restrict__ W,
    const int* __restrict__ order,
    float* __restrict__ out)
{
    __shared__ float xs[NHID];
    __shared__ float pk[3];

    const int bidx = blockIdx.x;
    // XCD swizzle: blocks round-robin over 8 XCDs; give XCD (b&7) the
    // contiguous sorted-rank range [512*(b&7), ...) for L2-local node reuse.
    const int r  = (bidx & 7) * (BATCH / 8) + (bidx >> 3);
    const int b  = order[r];
    const int tid = threadIdx.x;

    if (tid < NHID / 4) {
        ((float4*)xs)[tid] = ((const float4*)(inputs + (size_t)b * NHID))[tid];
    }
    __syncthreads();

    const int k    = tid >> 6;   // wave index = tree level (0..2)
    const int lane = tid & 63;
    const int lab  = labels[b];

    int node, step;
    if (k == 0)      { node = 0;                 step = (lab >> 10) & 31; }
    else if (k == 1) { node = 1 + (lab >> 10);   step = (lab >> 5)  & 31; }
    else             { node = 33 + (lab >> 5);   step = lab & 31;         }

    // Lane layout: col group (4 cols) = lane&7, h-strip = lane>>3 (h = strip + 8*i)
    const int colg  = lane & 7;
    const int hbase = lane >> 3;
    const float4* wp = (const float4*)(W + (size_t)node * (NHID * BR) + hbase * BR + colg * 4);

    float a0 = 0.f, a1 = 0.f, a2 = 0.f, a3 = 0.f;
    #pragma unroll 8
    for (int i = 0; i < NHID / 8; ++i) {
        float4 w = wp[i * (8 * BR / 4)];   // stride 8 h-rows = 64 float4
        float  x = xs[hbase + 8 * i];
        a0 = fmaf(x, w.x, a0);
        a1 = fmaf(x, w.y, a1);
        a2 = fmaf(x, w.z, a2);
        a3 = fmaf(x, w.w, a3);
    }

    // Butterfly reduce over the 8 h-strips (xor masks 8,16,32)
    for (int m = 8; m <= 32; m <<= 1) {
        a0 += __shfl_xor(a0, m);
        a1 += __shfl_xor(a1, m);
        a2 += __shfl_xor(a2, m);
        a3 += __shfl_xor(a3, m);
    }

    // Softmax over 32 logits spread as 8 groups x 4 values.
    float mx = fmaxf(fmaxf(a0, a1), fmaxf(a2, a3));
    for (int m = 1; m <= 4; m <<= 1) mx = fmaxf(mx, __shfl_xor(mx, m));
    float es = expf(a0 - mx) + expf(a1 - mx) + expf(a2 - mx) + expf(a3 - mx);
    for (int m = 1; m <= 4; m <<= 1) es += __shfl_xor(es, m);

    const int e = step & 3;
    float v = (e == 0) ? a0 : (e == 1) ? a1 : (e == 2) ? a2 : a3;
    float sl = __shfl(v, step >> 2);
    float p = expf(sl - mx) / es;

    if (lane == 0) pk[k] = p;
    __syncthreads();
    if (tid == 0) out[b] = pk[0] * pk[1] * pk[2];
}

extern "C" void kernel_launch(void* const* d_in, const int* in_sizes, int n_in,
                              void* d_out, int out_size, void* d_ws, size_t ws_size,
                              hipStream_t stream)
{
    const float* inputs = (const float*)d_in[0];
    const int*   labels = (const int*)d_in[1];
    const float* W      = (const float*)d_in[2];
    float* out = (float*)d_out;
    int* order = (int*)d_ws;   // 16 KB

    k_sort    <<<dim3(1),     dim3(1024), 0, stream>>>(labels, order);
    hsm_kernel<<<dim3(BATCH), dim3(192),  0, stream>>>(inputs, labels, W, order, out);
}